// Round 1
// baseline (197.713 us; speedup 1.0000x reference)
//
#include <hip/hip_runtime.h>
#include <hip/hip_bf16.h>

// InstanceAttentionModule: B=32, H=W=32 (HW=1024), C=256, F=64, K_NEIGH=32.
// Round-9:
//   k_lin    : sq and T now written PRE-SCALED by log2(e) (consumed only by
//              k_scores) -> k_scores runs entirely in exp2 domain
//   k_scores : MFMA operands SWAPPED (g = mfma(jfrag, ifrag)) so each lane
//              owns 4 consecutive j of one row:
//                - E written as packed b64 via v_cvt_pk_bf16_f32 (was 4x
//                  scalar f2bf + ds_write_u16)
//                - sq[j] loaded as one float4 per group (was 1 scalar/iter
//                  + per-r subs)
//                - dy hoisted per group; row-sum is a scalar (2 shuffles)
//                - all exps are raw v_exp_f32 (no v_mul per __expf)
//              pass 2 packs u via cvt_pk pairs; Z still sums ROUNDED u
//   k_out    : 2-phase prefetch double-buffer (STAGE t+1 issued before
//              compute t, ONE barrier per K-step instead of two)

typedef short bf16x8 __attribute__((ext_vector_type(8)));
typedef float f32x4 __attribute__((ext_vector_type(4)));

#define LOG2E 1.4426950408889634f

__device__ __forceinline__ unsigned short f2bf(float f) {
  unsigned u = __float_as_uint(f);
  u += 0x7fffu + ((u >> 16) & 1u);   // round-to-nearest-even
  return (unsigned short)(u >> 16);
}
__device__ __forceinline__ float bf2f(unsigned short h) {
  return __uint_as_float(((unsigned)h) << 16);
}
__device__ __forceinline__ unsigned pack2(float a, float b) {
  return (unsigned)f2bf(a) | ((unsigned)f2bf(b) << 16);
}
__device__ __forceinline__ unsigned cvtpk(float lo, float hi) {
  unsigned r;
  asm("v_cvt_pk_bf16_f32 %0, %1, %2" : "=v"(r) : "v"(lo), "v"(hi));
  return r;
}
__device__ __forceinline__ float exp2x(float x) {   // 2^x, single v_exp_f32
  float r;
  asm("v_exp_f32 %0, %1" : "=v"(r) : "v"(x));
  return r;
}
__device__ __forceinline__ f32x4 mfma16(bf16x8 a, bf16x8 b, f32x4 c) {
  return __builtin_amdgcn_mfma_f32_16x16x32_bf16(a, b, c, 0, 0, 0);
}
__device__ __forceinline__ int iabs(int v) { return v < 0 ? -v : v; }
__device__ __forceinline__ void load_lds16(const void* g, void* l) {
  __builtin_amdgcn_global_load_lds(
      (const __attribute__((address_space(1))) unsigned int*)g,
      (__attribute__((address_space(3))) unsigned int*)l, 16, 0, 0);
}

// ---------------------------------------------------------------- k_prep
// grid 80 x 256, 4 elems/thread: Wb = bf16(embW rows 0..63 || attnW rows 64..319)
__global__ __launch_bounds__(256) void k_prep(const float* __restrict__ embW,
                                              const float* __restrict__ attnW,
                                              unsigned short* __restrict__ Wb) {
  const int i = (blockIdx.x * 256 + threadIdx.x) * 4;   // 0..81916
  float4 v = (i < 16384) ? *(const float4*)(embW + i)
                         : *(const float4*)(attnW + (i - 16384));
  ushort4 p; p.x = f2bf(v.x); p.y = f2bf(v.y); p.z = f2bf(v.z); p.w = f2bf(v.w);
  *(ushort4*)(Wb + i) = p;
}

// ---------------------------------------------------------------- k_lin
// Fused emb+shortcut. grid 512 (64-row M-tiles), block 256 = 4 waves (2x2).
// sq2 and T2 outputs are PRE-SCALED by log2(e) for k_scores' exp2 domain.
__global__ __launch_bounds__(256) void k_lin(const float* __restrict__ x,
                                             const unsigned short* __restrict__ Wb,
                                             const float* __restrict__ embB,
                                             const float* __restrict__ attnB,
                                             const float* __restrict__ thrW,
                                             const float* __restrict__ thrB,
                                             unsigned short* __restrict__ embb,
                                             float* __restrict__ sq2,
                                             unsigned short* __restrict__ scT,
                                             float* __restrict__ T2out) {
  __shared__ union {
    struct { unsigned short xs[64][40]; unsigned short ws[320][40]; } a;
    unsigned short St[256][72];
  } sm;
  const int t = threadIdx.x;
  const int Mbase = blockIdx.x * 64;
  const int lane = t & 63, wave = t >> 6;
  const int wm = wave >> 1, wn = wave & 1;
  const int l15 = lane & 15, quad = lane >> 4;

  f32x4 acc[2][10] = {};
  for (int k0 = 0; k0 < 256; k0 += 32) {
    { // stage x tile (64x32) from fp32, convert inline
      int row = t >> 2, c0 = (t & 3) * 8;
      const float* src = x + (size_t)(Mbase + row) * 256 + k0 + c0;
      float4 a = *(const float4*)src;
      float4 b = *(const float4*)(src + 4);
      uint4 p; p.x = pack2(a.x, a.y); p.y = pack2(a.z, a.w);
      p.z = pack2(b.x, b.y); p.w = pack2(b.z, b.w);
      *(uint4*)&sm.a.xs[row][c0] = p;
    }
    { // stage weight tile (320x32): pure copies from pre-converted Wb
      const unsigned short* wsrc = Wb + (size_t)t * 256 + k0;
      for (int s = 0; s < 4; s++)
        *(uint4*)&sm.a.ws[t][s * 8] = *(const uint4*)(wsrc + s * 8);
      if (t < 64) {
        const unsigned short* wsrc2 = Wb + (size_t)(256 + t) * 256 + k0;
        for (int s = 0; s < 4; s++)
          *(uint4*)&sm.a.ws[256 + t][s * 8] = *(const uint4*)(wsrc2 + s * 8);
      }
    }
    __syncthreads();
    bf16x8 af[2];
    af[0] = *(const bf16x8*)&sm.a.xs[wm * 32 + l15][quad * 8];
    af[1] = *(const bf16x8*)&sm.a.xs[wm * 32 + 16 + l15][quad * 8];
    for (int nt = 0; nt < 10; nt++) {
      bf16x8 bfr = *(const bf16x8*)&sm.a.ws[wn * 160 + nt * 16 + l15][quad * 8];
      acc[0][nt] = mfma16(af[0], bfr, acc[0][nt]);
      acc[1][nt] = mfma16(af[1], bfr, acc[1][nt]);
    }
    __syncthreads();
  }

  // emb epilogue: wn==0 waves own n<64 (nt 0..3); sq2 from ROUNDED emb.
  if (wn == 0) {
    float sp[2][4] = {{0.f,0.f,0.f,0.f},{0.f,0.f,0.f,0.f}};
    for (int rt = 0; rt < 2; rt++)
      for (int nt = 0; nt < 4; nt++) {
        int n = nt * 16 + l15;
        float bias = embB[n];
        for (int r = 0; r < 4; r++) {
          float v = acc[rt][nt][r] + bias;
          unsigned short hb = f2bf(v);
          int row = wm * 32 + rt * 16 + quad * 4 + r;
          embb[(size_t)(Mbase + row) * 64 + n] = hb;
          float vf = bf2f(hb);
          sp[rt][r] += vf * vf;
        }
      }
    for (int m = 8; m >= 1; m >>= 1)
      for (int rt = 0; rt < 2; rt++)
        for (int r = 0; r < 4; r++)
          sp[rt][r] += __shfl_xor(sp[rt][r], m);
    if (l15 == 0)
      for (int rt = 0; rt < 2; rt++)
        for (int r = 0; r < 4; r++)
          sq2[Mbase + wm * 32 + rt * 16 + quad * 4 + r] = sp[rt][r] * LOG2E;
  }

  // shortcut epilogue -> St transpose buffer
  for (int rt = 0; rt < 2; rt++)
    for (int nt = 0; nt < 10; nt++) {
      int n = wn * 160 + nt * 16 + l15;
      if (n < 64) continue;
      int c = n - 64;
      float bias = attnB[c];
      for (int r = 0; r < 4; r++) {
        float v = acc[rt][nt][r] + bias;
        sm.St[c][wm * 32 + rt * 16 + quad * 4 + r] = f2bf(v);
      }
    }
  __syncthreads();

  const int b = Mbase >> 10, jbase = Mbase & 1023;
  { // coalesced write of scT[b][c][jbase..jbase+64)
    unsigned short* dst = scT + ((size_t)b * 256 + t) * 1024 + jbase;
    for (int s = 0; s < 8; s++)
      *(uint4*)(dst + s * 8) = *(const uint4*)&sm.St[t][s * 8];
  }
  { // Tinst (pre-scaled by log2e)
    float tp = 0.f;
    int j = t >> 2, cs = (t & 3) * 64;
    for (int c = 0; c < 64; c++)
      tp += bf2f(sm.St[cs + c][j]) * thrW[cs + c];
    tp += __shfl_xor(tp, 1);
    tp += __shfl_xor(tp, 2);
    if ((t & 3) == 0) T2out[Mbase + j] = (tp + thrB[0]) * LOG2E;
  }
}

// ---------------------------------------------------------------- k_scores
// grid 2048 (32 b x 64 strips of 16 rows), block 512 = 8 waves.
// Pass 1 (SWAPPED operands): g = mfma(jfrag, ifrag) -> lane owns row i=rb+l15,
//   cols j = j0 + quad*4 + r (4 consecutive). E packed to b64 via cvt_pk.
//   All math in exp2 domain (sq2/T2 pre-scaled by log2e).
// Pass 2: thread (row=t>>5, seg=t&31): u = exp2(relu(E*invR2 - T2)) -> U, Z.
__global__ __launch_bounds__(512) void k_scores(const unsigned short* __restrict__ embb,
                                                const float* __restrict__ sq2,
                                                const float* __restrict__ T2,
                                                unsigned short* __restrict__ U,
                                                float* __restrict__ Z) {
  __shared__ unsigned short E_lds[16 * 1040];   // 33280 B
  __shared__ float rbuf[16];
  __shared__ float lm2[64];                     // (m(diff)-1)*log2e, diff 0..62
  const int t = threadIdx.x, lane = t & 63, wave = t >> 6;
  const int b = blockIdx.x >> 6, rb = (blockIdx.x & 63) * 16;
  const int l15 = lane & 15, quad = lane >> 4;
  const unsigned short* eb = embb + (size_t)b * 1024 * 64;
  const float* sq2b = sq2 + b * 1024;

  if (t < 16) rbuf[t] = 0.f;
  if (t < 64) {
    float m = (t <= 32) ? (float)t * (1.f / 32.f) : 0.f;
    lm2[t] = (m - 1.f) * LOG2E;
  }
  __syncthreads();   // lm2 + rbuf visible

  // ---- pass 1: lane's fixed row i (output COL side of swapped MFMA)
  const int i = rb + l15;
  bf16x8 if0 = *(const bf16x8*)(eb + (size_t)i * 64 + quad * 8);
  bf16x8 if1 = *(const bf16x8*)(eb + (size_t)i * 64 + 32 + quad * 8);
  const float nsq2i = -sq2b[i];
  const int yi = i >> 5, xi = i & 31;   // yi constant across strip (16 | 32)
  const int jq = wave * 128;
  float rp = 0.f;
  #pragma unroll
  for (int j0 = jq; j0 < jq + 128; j0 += 16) {
    const int jr = j0 + l15;
    bf16x8 jf0 = *(const bf16x8*)(eb + (size_t)jr * 64 + quad * 8);
    bf16x8 jf1 = *(const bf16x8*)(eb + (size_t)jr * 64 + 32 + quad * 8);
    f32x4 g = {0.f, 0.f, 0.f, 0.f};
    g = mfma16(jf0, if0, g);          // row side = j, col side = i
    g = mfma16(jf1, if1, g);
    const int jg = j0 + quad * 4;     // lane's 4 j's: jg..jg+3 (no y-wrap)
    const float4 s4 = *(const float4*)(sq2b + jg);
    const int dy = iabs(yi - (jg >> 5));
    const int dxa = xi - (jg & 31);
    float e0, e1, e2, e3;
    {
      float w2 = fminf(fmaf(2.f * LOG2E, g[0], nsq2i - s4.x), 0.f);
      e0 = exp2x(fmaf(exp2x(w2), LOG2E, lm2[dy + iabs(dxa)]));
      w2 = fminf(fmaf(2.f * LOG2E, g[1], nsq2i - s4.y), 0.f);
      e1 = exp2x(fmaf(exp2x(w2), LOG2E, lm2[dy + iabs(dxa - 1)]));
      w2 = fminf(fmaf(2.f * LOG2E, g[2], nsq2i - s4.z), 0.f);
      e2 = exp2x(fmaf(exp2x(w2), LOG2E, lm2[dy + iabs(dxa - 2)]));
      w2 = fminf(fmaf(2.f * LOG2E, g[3], nsq2i - s4.w), 0.f);
      e3 = exp2x(fmaf(exp2x(w2), LOG2E, lm2[dy + iabs(dxa - 3)]));
    }
    rp += (e0 + e1) + (e2 + e3);      // unrounded sum (as before)
    uint2 pk; pk.x = cvtpk(e0, e1); pk.y = cvtpk(e2, e3);
    *(uint2*)&E_lds[l15 * 1040 + jg] = pk;   // conflict-free b64
  }
  rp += __shfl_xor(rp, 16);
  rp += __shfl_xor(rp, 32);
  __syncthreads();   // E_lds writes complete
  if (quad == 0) atomicAdd(&rbuf[l15], rp);
  __syncthreads();   // R complete

  // ---- pass 2: row = t>>5 (0..15), seg = t&31 (0..31)
  const int prow = t >> 5, seg = t & 31;
  const float invR2 = LOG2E / rbuf[prow];
  const float* T2b = T2 + b * 1024;
  unsigned short* ur = U + ((size_t)(b * 1024 + rb + prow)) * 1024;
  float z = 0.f;
  #pragma unroll
  for (int c = 0; c < 4; c++) {
    int j = c * 256 + seg * 8;
    union { bf16x8 v; unsigned short s[8]; } ev;
    ev.v = *(const bf16x8*)&E_lds[prow * 1040 + j];
    float4 t0 = *(const float4*)(T2b + j);
    float4 t1 = *(const float4*)(T2b + j + 4);
    float tf[8] = {t0.x, t0.y, t0.z, t0.w, t1.x, t1.y, t1.z, t1.w};
    uint4 uo;
    unsigned q[4];
    #pragma unroll
    for (int h = 0; h < 4; h++) {
      float u0 = exp2x(fmaxf(fmaf(bf2f(ev.s[2 * h]), invR2, -tf[2 * h]), 0.f));
      float u1 = exp2x(fmaxf(fmaf(bf2f(ev.s[2 * h + 1]), invR2, -tf[2 * h + 1]), 0.f));
      unsigned qq = cvtpk(u0, u1);
      q[h] = qq;
      // Z sums the ROUNDED u used by the GEMM
      z += __uint_as_float(qq << 16) + __uint_as_float(qq & 0xffff0000u);
    }
    uo.x = q[0]; uo.y = q[1]; uo.z = q[2]; uo.w = q[3];
    *(uint4*)(ur + j) = uo;
  }
  z += __shfl_xor(z, 1);
  z += __shfl_xor(z, 2);
  z += __shfl_xor(z, 4);
  z += __shfl_xor(z, 8);
  z += __shfl_xor(z, 16);
  if (seg == 0) Z[b * 1024 + rb + prow] = z;
}

// ---------------------------------------------------------------- k_out
// out = x + (U @ scT^T) * invZ.  2-phase prefetch double-buffer:
// STAGE(t+1) issued BEFORE compute(t); ONE __syncthreads per K-step
// (its implicit vmcnt(0)+lgkmcnt(0) drain is the buffer handoff).
__global__ __launch_bounds__(256) void k_out(const unsigned short* __restrict__ U,
                                             const float* __restrict__ Z,
                                             const unsigned short* __restrict__ scT,
                                             const float* __restrict__ x,
                                             float* __restrict__ out) {
  __shared__ unsigned short Ab[2][128 * 32];
  __shared__ unsigned short Bb[2][128 * 32];
  const int t = threadIdx.x, lane = t & 63, wave = t >> 6;
  const int wm = wave >> 1, wn = wave & 1;
  const int l15 = lane & 15, quad = lane >> 4;
  const int x8 = blockIdx.x & 7, s = blockIdx.x >> 3;
  const int b = x8 * 4 + (s >> 4), tile = s & 15;
  const int rb = (tile >> 1) * 128, cb = (tile & 1) * 128;

  const unsigned short* Ubase = U + (size_t)b * 1024 * 1024 + (size_t)rb * 1024;
  const unsigned short* Sbase = scT + (size_t)b * 256 * 1024 + (size_t)cb * 1024;

  const int c0 = wave * 64 + lane;
  const int c1 = c0 + 256;
  const int r0 = c0 >> 2, o0 = (c0 & 3) * 8;
  const int r1 = c1 >> 2, o1 = (c1 & 3) * 8;
  const unsigned short* ua0 = Ubase + (size_t)r0 * 1024 + o0;
  const unsigned short* ua1 = Ubase + (size_t)r1 * 1024 + o1;
  const unsigned short* sa0 = Sbase + (size_t)r0 * 1024 + o0;
  const unsigned short* sa1 = Sbase + (size_t)r1 * 1024 + o1;

#define STAGE(bufi, j0)                              \
  do {                                               \
    load_lds16(ua0 + (j0), &Ab[bufi][c0 * 8]);       \
    load_lds16(ua1 + (j0), &Ab[bufi][c1 * 8]);       \
    load_lds16(sa0 + (j0), &Bb[bufi][c0 * 8]);       \
    load_lds16(sa1 + (j0), &Bb[bufi][c1 * 8]);       \
  } while (0)

  f32x4 acc[4][4] = {};
  STAGE(0, 0);
  __syncthreads();                      // drains vmcnt: buf0 ready
  int cur = 0;
  for (int it = 0; it < 32; ++it) {
    if (it < 31) STAGE(cur ^ 1, (it + 1) * 32);   // prefetch next K-step
    bf16x8 af[4], bfr[4];
    for (int i = 0; i < 4; i++)
      af[i] = *(const bf16x8*)&Ab[cur][(wm * 64 + i * 16 + l15) * 32 + quad * 8];
    for (int i = 0; i < 4; i++)
      bfr[i] = *(const bf16x8*)&Bb[cur][(wn * 64 + i * 16 + l15) * 32 + quad * 8];
    for (int i = 0; i < 4; i++)
      for (int j = 0; j < 4; j++)
        acc[i][j] = mfma16(af[i], bfr[j], acc[i][j]);
    if (it < 31) {
      __syncthreads();                  // drain prefetch + protect cur buf
      cur ^= 1;
    }
  }
#undef STAGE

  const int colb = cb + wn * 64;
  for (int i = 0; i < 4; i++) {
    int rowb = rb + wm * 64 + i * 16 + quad * 4;
    float iz[4];
    for (int r = 0; r < 4; r++) iz[r] = 1.f / Z[b * 1024 + rowb + r];
    for (int j = 0; j < 4; j++) {
      int c = colb + j * 16 + l15;
      for (int r = 0; r < 4; r++) {
        size_t idx = ((size_t)(b * 1024 + rowb + r)) * 256 + c;
        out[idx] = x[idx] + acc[i][j][r] * iz[r];
      }
    }
  }
}

// ---------------------------------------------------------------- launch
extern "C" void kernel_launch(void* const* d_in, const int* in_sizes, int n_in,
                              void* d_out, int out_size, void* d_ws, size_t ws_size,
                              hipStream_t stream) {
  const float* x     = (const float*)d_in[0];
  const float* embW  = (const float*)d_in[1];
  const float* embB  = (const float*)d_in[2];
  const float* attnW = (const float*)d_in[3];
  const float* attnB = (const float*)d_in[4];
  const float* thrW  = (const float*)d_in[5];
  const float* thrB  = (const float*)d_in[6];
  float* out = (float*)d_out;

  char* ws = (char*)d_ws;
  // layout: embb 4MB | scT 16MB | U 64MB | sq2/T2/Z tail
  // Wb (160KB) OVERLAPS U: dead before k_scores writes U.
  unsigned short* embb = (unsigned short*)(ws);
  unsigned short* scT  = (unsigned short*)(ws + (4ull << 20));
  unsigned short* U    = (unsigned short*)(ws + (20ull << 20));
  unsigned short* Wb   = (unsigned short*)(ws + (36ull << 20));   // overlap
  float* sq2 = (float*)(ws + (84ull << 20));
  float* T2  = (float*)(ws + (84ull << 20) + (128ull << 10));
  float* Z   = (float*)(ws + (84ull << 20) + (256ull << 10));

  k_prep<<<80, 256, 0, stream>>>(embW, attnW, Wb);
  k_lin<<<512, 256, 0, stream>>>(x, Wb, embB, attnB, thrW, thrB, embb, sq2, scT, T2);
  k_scores<<<2048, 512, 0, stream>>>(embb, sq2, T2, U, Z);
  k_out<<<512, 256, 0, stream>>>(U, Z, scT, x, out);
}